// Round 13
// baseline (138.172 us; speedup 1.0000x reference)
//
#include <hip/hip_runtime.h>
#include <hip/hip_bf16.h>

#define GAT_N 8192
#define GAT_K 256
#define GAT_D 64
#define GAT_ALPHA 0.2f
#define GAT_FILL 1e-15f

typedef float f32x4 __attribute__((ext_vector_type(4)));
typedef short bf16x8 __attribute__((ext_vector_type(8)));

static __device__ __forceinline__ unsigned f2bf_u(float x) {
  unsigned u = __float_as_uint(x);
  u += 0x7FFFu + ((u >> 16) & 1u);
  return u >> 16;
}

// ---------------------------------------------------------------------------
// Kernel 1: register-tiled Wh = h @ W. WhT is now CHUNK-TILED:
//   WhT_t[c][d][j'] with c = j>>9 (16 chunks of 512 cols), d = 0..63,
//   j' = j&511. Row stride inside a tile = 1 KB (was 16 KB) -> B-fragment
//   gathers in k_attn spread across L2 banks instead of serializing.
// ---------------------------------------------------------------------------
__global__ __launch_bounds__(256) void k_prep(const float* __restrict__ h,
                                              const float* __restrict__ W,
                                              const float* __restrict__ av,
                                              float* __restrict__ s_src,
                                              float* __restrict__ s_dst,
                                              short* __restrict__ WhT,
                                              float* __restrict__ bmax) {
  __shared__ short T[4][64][8];
  __shared__ float wmLds[4];
  const int tid = threadIdx.x;
  const int wv = tid >> 6, lane = tid & 63;
  const int r0 = blockIdx.x * 32 + wv * 8;

  float acc[8], acc2[8];
#pragma unroll
  for (int r = 0; r < 8; ++r) { acc[r] = 0.f; acc2[r] = 0.f; }

  for (int kc = 0; kc < GAT_K; kc += 32) {
    float Wreg[32];
#pragma unroll
    for (int e = 0; e < 32; ++e) Wreg[e] = W[(size_t)(kc + e) * GAT_D + lane];
#pragma unroll
    for (int r = 0; r < 8; ++r) {
      const f32x4* h4 = (const f32x4*)(h + (size_t)(r0 + r) * GAT_K + kc);
#pragma unroll
      for (int q = 0; q < 8; ++q) {
        f32x4 hv = h4[q];
        acc[r] += hv[0] * Wreg[4 * q + 0];
        acc2[r] += hv[1] * Wreg[4 * q + 1];
        acc[r] += hv[2] * Wreg[4 * q + 2];
        acc2[r] += hv[3] * Wreg[4 * q + 3];
      }
    }
  }

  const float a_s = av[lane];
  const float a_d = av[64 + lane];
  float wmax = -3.0e38f;
#pragma unroll
  for (int r = 0; r < 8; ++r) {
    const float accf = acc[r] + acc2[r];
    T[wv][lane][r] = (short)f2bf_u(accf);
    float vs = accf * a_s, vd = accf * a_d;
#pragma unroll
    for (int off = 32; off > 0; off >>= 1) {
      vs += __shfl_xor(vs, off);
      vd += __shfl_xor(vd, off);
    }
    if (lane == 0) { s_src[r0 + r] = vs; s_dst[r0 + r] = vd; }
    wmax = fmaxf(wmax, vd);
  }
  bf16x8 vt = *(const bf16x8*)&T[wv][lane][0];
  // tiled write: chunk = r0>>9, in-chunk col = r0&511 (8 cols, same chunk)
  *(bf16x8*)(WhT + (size_t)(r0 >> 9) * 32768 + (size_t)lane * 512 + (r0 & 511)) = vt;

  if (lane == 0) wmLds[wv] = wmax;
  __syncthreads();
  if (tid == 0) {
    bmax[blockIdx.x] = fmaxf(fmaxf(wmLds[0], wmLds[1]), fmaxf(wmLds[2], wmLds[3]));
  }
}

// ---------------------------------------------------------------------------
// Kernel 2: register-deep barrier-free fused masked-softmax + P@Wh.
//   512 blocks x 256 thr (4 waves, launch_bounds(256,2) -> 256 VGPR cap).
//   16 chunks of 512 cols, visited in per-block ROTATED order
//   (rot = blockIdx&15) to spread HBM channel pressure.
//   A prefetch depth TWO chunks (ArA/ArB, statically indexed via 2x-unrolled
//   loop); B (tiled WhT) and t prefetch depth one. Row constants in a 256 B
//   LDS table (saves ~32 VGPRs). Wave-private 4 KB XOR-swizzled P tiles,
//   no barrier in the loop. Fixed-shift factorized softmax (validated):
//     P = edge ? (t >= -s ? E1_j*F1_r : E2_j*F2_r) : cc_r
// ---------------------------------------------------------------------------
#define BM 16

__global__ __launch_bounds__(256, 2) void k_attn(
    const float* __restrict__ A,
    const float* __restrict__ s_src,
    const float* __restrict__ s_dst,
    const short* __restrict__ WhT,
    const float* __restrict__ bmax,
    float* __restrict__ out) {
  __shared__ char smem[16896];  // 4x4KB tiles | lds_l @16384 | scon @16640

  const int tid = threadIdx.x;
  const int wv = tid >> 6, lane = tid & 63;
  const int hi = lane >> 5, l5 = lane & 31;
  const int rsub = lane & 15, kg = lane >> 4;
  const int i0 = blockIdx.x * BM;
  const int wvbase = wv << 12;
  const int rot = blockIdx.x & 15;

  float* scon = (float*)(smem + 16640);  // F1[16]|F2[16]|ns[16]|cc[16]

  // global max of s_dst from 256 per-block maxima
  float bm = fmaxf(fmaxf(bmax[lane], bmax[lane + 64]),
                   fmaxf(bmax[lane + 128], bmax[lane + 192]));
#pragma unroll
  for (int off = 32; off > 0; off >>= 1) bm = fmaxf(bm, __shfl_xor(bm, off));
  const float tmax = bm;

  if (tid < BM) {
    float sc = s_src[i0 + tid];
    float x0 = sc + tmax;
    float m = fmaxf(fmaxf(x0, GAT_ALPHA * x0), GAT_FILL);
    scon[tid] = __expf(sc - m);
    scon[16 + tid] = __expf(GAT_ALPHA * sc - m);
    scon[32 + tid] = -sc;
    scon[48 + tid] = __expf(GAT_FILL - m);
  }
  __syncthreads();  // scon ready (only barrier before epilogue)

  bf16x8 ones;
#pragma unroll
  for (int e = 0; e < 8; ++e) ones[e] = (short)0x3F80;

  f32x4 acc0 = {0.f, 0.f, 0.f, 0.f};
  f32x4 acc1 = {0.f, 0.f, 0.f, 0.f};
  f32x4 acc2 = {0.f, 0.f, 0.f, 0.f};
  f32x4 acc3 = {0.f, 0.f, 0.f, 0.f};
  f32x4 accl = {0.f, 0.f, 0.f, 0.f};

  // bases (per-chunk offsets added in-loop)
  const float* Abase = A + (size_t)(i0 + hi) * GAT_N + wv * 128 + l5 * 4;
  const short* pB0 = WhT + (size_t)(0 * 16 + rsub) * 512 + wv * 128 + (kg << 3);
  const short* pB1 = WhT + (size_t)(1 * 16 + rsub) * 512 + wv * 128 + (kg << 3);
  const short* pB2 = WhT + (size_t)(2 * 16 + rsub) * 512 + wv * 128 + (kg << 3);
  const short* pB3 = WhT + (size_t)(3 * 16 + rsub) * 512 + wv * 128 + (kg << 3);
  const float* tbase = s_dst + wv * 128 + l5 * 4;

  // ---- prologue: A chunks rot, rot+1; B + t chunk rot ----
  f32x4 ArA[8], ArB[8];
  bf16x8 bq0[4], bq1[4], bq2[4], bq3[4];
  f32x4 tcur;
  {
    const int cc0 = rot, cc1 = (rot + 1) & 15;
#pragma unroll
    for (int s = 0; s < 8; ++s) {
      ArA[s] = *(const f32x4*)(Abase + (size_t)(2 * s) * GAT_N + cc0 * 512);
      ArB[s] = *(const f32x4*)(Abase + (size_t)(2 * s) * GAT_N + cc1 * 512);
    }
#pragma unroll
    for (int kq = 0; kq < 4; ++kq) {
      bq0[kq] = *(const bf16x8*)(pB0 + cc0 * 32768 + (kq << 5));
      bq1[kq] = *(const bf16x8*)(pB1 + cc0 * 32768 + (kq << 5));
      bq2[kq] = *(const bf16x8*)(pB2 + cc0 * 32768 + (kq << 5));
      bq3[kq] = *(const bf16x8*)(pB3 + cc0 * 32768 + (kq << 5));
    }
    tcur = *(const f32x4*)(tbase + cc0 * 512);
  }

  auto chunk_body = [&](int c, f32x4 (&Ar)[8]) {
    const int cn1 = (c + 1 + rot) & 15;  // next chunk (B, t)
    const int cn2 = (c + 2 + rot) & 15;  // chunk after next (A)
    f32x4 tnxt = *(const f32x4*)(tbase + cn1 * 512);

    f32x4 E1, E2;
#pragma unroll
    for (int e = 0; e < 4; ++e) {
      E1[e] = __expf(tcur[e]);
      E2[e] = __expf(GAT_ALPHA * tcur[e]);
    }

    // ---- stage: consume Ar[s] (chunk c), re-issue for chunk c+2 ----
#pragma unroll
    for (int s = 0; s < 8; ++s) {
      f32x4 av = Ar[s];
      Ar[s] = *(const f32x4*)(Abase + (size_t)(2 * s) * GAT_N + cn2 * 512);
      const int row = 2 * s + hi;
      const float F1 = scon[row], F2 = scon[16 + row];
      const float negs = scon[32 + row], cv = scon[48 + row];
      float p[4];
#pragma unroll
      for (int e = 0; e < 4; ++e) {
        float m1 = E1[e] * F1;
        float m2 = E2[e] * F2;
        float psel = (tcur[e] >= negs) ? m1 : m2;
        p[e] = (av[e] > 0.f) ? psel : cv;
      }
      __hip_bfloat162 pa = __float22bfloat162_rn(float2{p[0], p[1]});
      __hip_bfloat162 pb = __float22bfloat162_rn(float2{p[2], p[3]});
      uint2 w;
      __builtin_memcpy(&w.x, &pa, 4);
      __builtin_memcpy(&w.y, &pb, 4);
      *(uint2*)(&smem[wvbase + (row << 8) + ((l5 << 3) ^ ((row & 7) << 4))]) = w;
    }

    // ---- MFMA: consume bq (chunk c), re-issue for chunk c+1 ----
#pragma unroll
    for (int kq = 0; kq < 4; ++kq) {
      const int raddr =
          wvbase + (rsub << 8) + (((kq << 6) | (kg << 4)) ^ ((rsub & 7) << 4));
      bf16x8 af = *(const bf16x8*)(&smem[raddr]);
      acc0 = __builtin_amdgcn_mfma_f32_16x16x32_bf16(af, bq0[kq], acc0, 0, 0, 0);
      acc1 = __builtin_amdgcn_mfma_f32_16x16x32_bf16(af, bq1[kq], acc1, 0, 0, 0);
      acc2 = __builtin_amdgcn_mfma_f32_16x16x32_bf16(af, bq2[kq], acc2, 0, 0, 0);
      acc3 = __builtin_amdgcn_mfma_f32_16x16x32_bf16(af, bq3[kq], acc3, 0, 0, 0);
      accl = __builtin_amdgcn_mfma_f32_16x16x32_bf16(af, ones, accl, 0, 0, 0);
      bq0[kq] = *(const bf16x8*)(pB0 + cn1 * 32768 + (kq << 5));
      bq1[kq] = *(const bf16x8*)(pB1 + cn1 * 32768 + (kq << 5));
      bq2[kq] = *(const bf16x8*)(pB2 + cn1 * 32768 + (kq << 5));
      bq3[kq] = *(const bf16x8*)(pB3 + cn1 * 32768 + (kq << 5));
    }
    tcur = tnxt;
  };

  // 2x-unrolled so the A double-buffer index is STATIC (no scratch spill)
  for (int cp = 0; cp < 8; ++cp) {
    chunk_body(2 * cp, ArA);
    chunk_body(2 * cp + 1, ArB);
  }

  __syncthreads();  // all waves done with tiles; reuse smem for epilogue

  // ---- epilogue: exact 4-wave combine + ELU ----
  float* lds_o = (float*)smem;            // [4][16][64] f32 = 16 KB
  float* lds_l = (float*)(smem + 16384);  // [4][16]
#pragma unroll
  for (int r = 0; r < 4; ++r) {
    const int orow = kg * 4 + r;  // C/D layout: col = lane&15, row = kg*4+reg
    lds_o[wv * 1024 + orow * 64 + 0 * 16 + rsub] = acc0[r];
    lds_o[wv * 1024 + orow * 64 + 1 * 16 + rsub] = acc1[r];
    lds_o[wv * 1024 + orow * 64 + 2 * 16 + rsub] = acc2[r];
    lds_o[wv * 1024 + orow * 64 + 3 * 16 + rsub] = acc3[r];
    if (rsub == 0) lds_l[wv * 16 + orow] = accl[r];
  }
  __syncthreads();

  for (int idx = tid; idx < BM * GAT_D; idx += 256) {
    const int r = idx >> 6, col = idx & 63;
    float o = 0.f, ll = 0.f;
#pragma unroll
    for (int w = 0; w < 4; ++w) {
      o += lds_o[w * 1024 + r * 64 + col];
      ll += lds_l[w * 16 + r];
    }
    float val = o / ll;
    out[(size_t)(i0 + r) * GAT_D + col] = (val > 0.f) ? val : (__expf(val) - 1.f);
  }
}

// ---------------------------------------------------------------------------
extern "C" void kernel_launch(void* const* d_in, const int* in_sizes, int n_in,
                              void* d_out, int out_size, void* d_ws, size_t ws_size,
                              hipStream_t stream) {
  const float* h = (const float*)d_in[0];
  const float* A = (const float*)d_in[1];
  const float* W = (const float*)d_in[2];
  const float* a = (const float*)d_in[3];
  float* out = (float*)d_out;

  // ws layout: [0,1K) bmax | [4K,+32K) s_src | [36864,+32K) s_dst | [69632,+1M) WhT
  const size_t need = 69632 + (size_t)GAT_D * GAT_N * 2;
  if (ws_size < need) return;
  float* bmax = (float*)d_ws;
  float* s_src = (float*)((char*)d_ws + 4096);
  float* s_dst = (float*)((char*)d_ws + 36864);
  short* WhT = (short*)((char*)d_ws + 69632);

  k_prep<<<dim3(256), dim3(256), 0, stream>>>(h, W, a, s_src, s_dst, WhT, bmax);
  k_attn<<<dim3(GAT_N / BM), dim3(256), 0, stream>>>(A, s_src, s_dst, WhT, bmax, out);
}

// Round 14
// 135.531 us; speedup vs baseline: 1.0195x; 1.0195x over previous
//
#include <hip/hip_runtime.h>
#include <hip/hip_bf16.h>

#define GAT_N 8192
#define GAT_K 256
#define GAT_D 64
#define GAT_ALPHA 0.2f
#define GAT_FILL 1e-15f

typedef float f32x4 __attribute__((ext_vector_type(4)));
typedef short bf16x8 __attribute__((ext_vector_type(8)));

typedef __attribute__((address_space(3))) unsigned char lds_byte;
typedef __attribute__((address_space(1))) const unsigned char glb_byte;

static __device__ __forceinline__ unsigned f2bf_u(float x) {
  unsigned u = __float_as_uint(x);
  u += 0x7FFFu + ((u >> 16) & 1u);
  return u >> 16;
}

// ---------------------------------------------------------------------------
// Kernel 1: register-tiled Wh = h @ W, chunk-tiled WhT (validated round 13):
//   WhT_t[c][d][j'] : c = j>>9 (16 chunks of 512), d=0..63, j'=j&511.
// ---------------------------------------------------------------------------
__global__ __launch_bounds__(256) void k_prep(const float* __restrict__ h,
                                              const float* __restrict__ W,
                                              const float* __restrict__ av,
                                              float* __restrict__ s_src,
                                              float* __restrict__ s_dst,
                                              short* __restrict__ WhT,
                                              float* __restrict__ bmax) {
  __shared__ short T[4][64][8];
  __shared__ float wmLds[4];
  const int tid = threadIdx.x;
  const int wv = tid >> 6, lane = tid & 63;
  const int r0 = blockIdx.x * 32 + wv * 8;

  float acc[8], acc2[8];
#pragma unroll
  for (int r = 0; r < 8; ++r) { acc[r] = 0.f; acc2[r] = 0.f; }

  for (int kc = 0; kc < GAT_K; kc += 32) {
    float Wreg[32];
#pragma unroll
    for (int e = 0; e < 32; ++e) Wreg[e] = W[(size_t)(kc + e) * GAT_D + lane];
#pragma unroll
    for (int r = 0; r < 8; ++r) {
      const f32x4* h4 = (const f32x4*)(h + (size_t)(r0 + r) * GAT_K + kc);
#pragma unroll
      for (int q = 0; q < 8; ++q) {
        f32x4 hv = h4[q];
        acc[r] += hv[0] * Wreg[4 * q + 0];
        acc2[r] += hv[1] * Wreg[4 * q + 1];
        acc[r] += hv[2] * Wreg[4 * q + 2];
        acc2[r] += hv[3] * Wreg[4 * q + 3];
      }
    }
  }

  const float a_s = av[lane];
  const float a_d = av[64 + lane];
  float wmax = -3.0e38f;
#pragma unroll
  for (int r = 0; r < 8; ++r) {
    const float accf = acc[r] + acc2[r];
    T[wv][lane][r] = (short)f2bf_u(accf);
    float vs = accf * a_s, vd = accf * a_d;
#pragma unroll
    for (int off = 32; off > 0; off >>= 1) {
      vs += __shfl_xor(vs, off);
      vd += __shfl_xor(vd, off);
    }
    if (lane == 0) { s_src[r0 + r] = vs; s_dst[r0 + r] = vd; }
    wmax = fmaxf(wmax, vd);
  }
  bf16x8 vt = *(const bf16x8*)&T[wv][lane][0];
  *(bf16x8*)(WhT + (size_t)(r0 >> 9) * 32768 + (size_t)lane * 512 + (r0 & 511)) = vt;

  if (lane == 0) wmLds[wv] = wmax;
  __syncthreads();
  if (tid == 0) {
    bmax[blockIdx.x] = fmaxf(fmaxf(wmLds[0], wmLds[1]), fmaxf(wmLds[2], wmLds[3]));
  }
}

// ---------------------------------------------------------------------------
// Kernel 2: async-DMA staged, barrier-free fused masked-softmax + P@Wh.
//   512 blocks x 512 thr (8 waves; 80 KB LDS -> 2 blocks/CU, 16 waves/CU).
//   16 chunks x 512 cols (rotated per block); wave wv owns a 64-col slice.
//   A: global_load_lds DMA into wave-private 2x4KB LDS double-buffer,
//      issued ONE CHUNK AHEAD (compiler cannot sink a DMA); consume via
//      contiguous ds_read_b128. Counted s_waitcnt vmcnt(4) (never 0) +
//      sched_barrier before reads; 2x-unrolled body -> static buf offsets.
//   P: wave-private 2 KB XOR-swizzled tile; B: chunk-tiled WhT (L2).
//   Fixed-shift factorized softmax (validated):
//     P = edge ? (t >= -s ? E1_j*F1_r : E2_j*F2_r) : cc_r
// ---------------------------------------------------------------------------
#define BM 16

__global__ __launch_bounds__(512, 4) void k_attn(
    const float* __restrict__ A,
    const float* __restrict__ s_src,
    const float* __restrict__ s_dst,
    const short* __restrict__ WhT,
    const float* __restrict__ bmax,
    float* __restrict__ out) {
  __shared__ char smem[81920];  // [0,64K) A dbufs (8KB/wave) | [64K,80K) P tiles

  const int tid = threadIdx.x;
  const int wv = tid >> 6, lane = tid & 63;
  const int sub = lane & 15, rg = lane >> 4;   // stage: col-group / row-group
  const int rsub = lane & 15, kg = lane >> 4;  // mfma: row / k-group
  const int i0 = blockIdx.x * BM;
  const int rot = blockIdx.x & 15;
  const int abase = wv * 8192;            // A double-buffer (2 x 4096)
  const int tbase = 65536 + wv * 2048;    // P tile

  // global max of s_dst from 256 per-block maxima
  float bm = fmaxf(fmaxf(bmax[lane], bmax[lane + 64]),
                   fmaxf(bmax[lane + 128], bmax[lane + 192]));
#pragma unroll
  for (int off = 32; off > 0; off >>= 1) bm = fmaxf(bm, __shfl_xor(bm, off));
  const float tmax = bm;

  // per-thread row constants (rows 4s + rg, s = 0..3)
  float F1_[4], F2_[4], ns_[4], cc_[4];
#pragma unroll
  for (int s = 0; s < 4; ++s) {
    const int row = 4 * s + rg;
    float sc = s_src[i0 + row];
    float x0 = sc + tmax;
    float m = fmaxf(fmaxf(x0, GAT_ALPHA * x0), GAT_FILL);
    F1_[s] = __expf(sc - m);
    F2_[s] = __expf(GAT_ALPHA * sc - m);
    ns_[s] = -sc;
    cc_[s] = __expf(GAT_FILL - m);
  }

  bf16x8 ones;
#pragma unroll
  for (int e = 0; e < 8; ++e) ones[e] = (short)0x3F80;

  f32x4 acc0 = {0.f, 0.f, 0.f, 0.f};
  f32x4 acc1 = {0.f, 0.f, 0.f, 0.f};
  f32x4 acc2 = {0.f, 0.f, 0.f, 0.f};
  f32x4 acc3 = {0.f, 0.f, 0.f, 0.f};
  f32x4 accl = {0.f, 0.f, 0.f, 0.f};

  // bases
  const float* Ab = A + (size_t)(i0 + rg) * GAT_N + wv * 64 + sub * 4;
  const short* pB0 = WhT + (size_t)(0 * 16 + rsub) * 512 + wv * 64 + (kg << 3);
  const short* pB1 = WhT + (size_t)(1 * 16 + rsub) * 512 + wv * 64 + (kg << 3);
  const short* pB2 = WhT + (size_t)(2 * 16 + rsub) * 512 + wv * 64 + (kg << 3);
  const short* pB3 = WhT + (size_t)(3 * 16 + rsub) * 512 + wv * 64 + (kg << 3);
  const float* tb = s_dst + wv * 64 + sub * 4;

  // DMA: 4 instructions cover 16 rows x 64 cols (4 KB) of chunk cg -> bufoff
  auto issue = [&](int cg, int bufoff) {
#pragma unroll
    for (int i = 0; i < 4; ++i) {
      const float* g = Ab + (size_t)(4 * i) * GAT_N + cg * 512;
      __builtin_amdgcn_global_load_lds(
          (glb_byte*)g, (lds_byte*)&smem[abase + bufoff + i * 1024], 16, 0, 0);
    }
  };

  issue(rot, 0);  // prologue: chunk rot -> buf0

  auto body = [&](int c, int bufR, int bufW) {
    const int cg = (c + rot) & 15;
    const int cn = (c + 1 + rot) & 15;
    const f32x4 t = *(const f32x4*)(tb + cg * 512);
    issue(cn, bufW);  // next chunk's DMA: in flight across this whole body
    asm volatile("s_waitcnt vmcnt(4)" ::: "memory");  // prev DMAs (bufR) done
    __builtin_amdgcn_sched_barrier(0);

    f32x4 E1, E2;
#pragma unroll
    for (int e = 0; e < 4; ++e) {
      E1[e] = __expf(t[e]);
      E2[e] = __expf(GAT_ALPHA * t[e]);
    }

    // ---- stage: 4 steps from LDS A-buf (contiguous b128, 2-way free) ----
#pragma unroll
    for (int s = 0; s < 4; ++s) {
      const f32x4 av =
          *(const f32x4*)(&smem[abase + bufR + s * 1024 + lane * 16]);
      float p[4];
#pragma unroll
      for (int e = 0; e < 4; ++e) {
        float m1 = E1[e] * F1_[s];
        float m2 = E2[e] * F2_[s];
        float psel = (t[e] >= ns_[s]) ? m1 : m2;
        p[e] = (av[e] > 0.f) ? psel : cc_[s];
      }
      __hip_bfloat162 pa = __float22bfloat162_rn(float2{p[0], p[1]});
      __hip_bfloat162 pb = __float22bfloat162_rn(float2{p[2], p[3]});
      uint2 w;
      __builtin_memcpy(&w.x, &pa, 4);
      __builtin_memcpy(&w.y, &pb, 4);
      const int row = 4 * s + rg;
      *(uint2*)(&smem[tbase + (row << 7) + ((sub << 3) ^ ((row & 7) << 4))]) = w;
    }

    // ---- MFMA: 2 k-quads; B from chunk-tiled WhT (L2-resident) ----
#pragma unroll
    for (int kq = 0; kq < 2; ++kq) {
      const int raddr =
          tbase + (rsub << 7) + (((kq << 6) | (kg << 4)) ^ ((rsub & 7) << 4));
      bf16x8 af = *(const bf16x8*)(&smem[raddr]);
      const int boff = cg * 32768 + (kq << 5);
      bf16x8 b0 = *(const bf16x8*)(pB0 + boff);
      bf16x8 b1 = *(const bf16x8*)(pB1 + boff);
      bf16x8 b2 = *(const bf16x8*)(pB2 + boff);
      bf16x8 b3 = *(const bf16x8*)(pB3 + boff);
      acc0 = __builtin_amdgcn_mfma_f32_16x16x32_bf16(af, b0, acc0, 0, 0, 0);
      acc1 = __builtin_amdgcn_mfma_f32_16x16x32_bf16(af, b1, acc1, 0, 0, 0);
      acc2 = __builtin_amdgcn_mfma_f32_16x16x32_bf16(af, b2, acc2, 0, 0, 0);
      acc3 = __builtin_amdgcn_mfma_f32_16x16x32_bf16(af, b3, acc3, 0, 0, 0);
      accl = __builtin_amdgcn_mfma_f32_16x16x32_bf16(af, ones, accl, 0, 0, 0);
    }
  };

  // 2x-unrolled: STATIC double-buffer offsets (alias-analysis friendly)
  for (int cp = 0; cp < 8; ++cp) {
    body(2 * cp, 0, 4096);
    body(2 * cp + 1, 4096, 0);
  }

  __syncthreads();  // drains final DMA (vmcnt 0 at barrier) + all tile use

  // ---- epilogue: exact 8-wave combine + ELU (smem reused) ----
  float* lds_o = (float*)smem;            // [8][16][64] f32 = 32 KB
  float* lds_l = (float*)(smem + 32768);  // [8][16]
#pragma unroll
  for (int r = 0; r < 4; ++r) {
    const int orow = kg * 4 + r;  // C/D layout: col = lane&15, row = kg*4+reg
    lds_o[wv * 1024 + orow * 64 + 0 * 16 + rsub] = acc0[r];
    lds_o[wv * 1024 + orow * 64 + 1 * 16 + rsub] = acc1[r];
    lds_o[wv * 1024 + orow * 64 + 2 * 16 + rsub] = acc2[r];
    lds_o[wv * 1024 + orow * 64 + 3 * 16 + rsub] = acc3[r];
    if (rsub == 0) lds_l[wv * 16 + orow] = accl[r];
  }
  __syncthreads();

  for (int idx = tid; idx < BM * GAT_D; idx += 512) {
    const int r = idx >> 6, col = idx & 63;
    float o = 0.f, ll = 0.f;
#pragma unroll
    for (int w = 0; w < 8; ++w) {
      o += lds_o[w * 1024 + r * 64 + col];
      ll += lds_l[w * 16 + r];
    }
    float val = o / ll;
    out[(size_t)(i0 + r) * GAT_D + col] = (val > 0.f) ? val : (__expf(val) - 1.f);
  }
}

// ---------------------------------------------------------------------------
extern "C" void kernel_launch(void* const* d_in, const int* in_sizes, int n_in,
                              void* d_out, int out_size, void* d_ws, size_t ws_size,
                              hipStream_t stream) {
  const float* h = (const float*)d_in[0];
  const float* A = (const float*)d_in[1];
  const float* W = (const float*)d_in[2];
  const float* a = (const float*)d_in[3];
  float* out = (float*)d_out;

  // ws layout: [0,1K) bmax | [4K,+32K) s_src | [36864,+32K) s_dst | [69632,+1M) WhT
  const size_t need = 69632 + (size_t)GAT_D * GAT_N * 2;
  if (ws_size < need) return;
  float* bmax = (float*)d_ws;
  float* s_src = (float*)((char*)d_ws + 4096);
  float* s_dst = (float*)((char*)d_ws + 36864);
  short* WhT = (short*)((char*)d_ws + 69632);

  k_prep<<<dim3(256), dim3(256), 0, stream>>>(h, W, a, s_src, s_dst, WhT, bmax);
  k_attn<<<dim3(GAT_N / BM), dim3(512), 0, stream>>>(A, s_src, s_dst, WhT, bmax, out);
}